// Round 3
// baseline (353.274 us; speedup 1.0000x reference)
//
#include <hip/hip_runtime.h>
#include <hip/hip_bf16.h>
#include <stdint.h>

typedef __bf16 bf16;
typedef bf16 bf16x8 __attribute__((ext_vector_type(8)));
typedef bf16 bf16x4 __attribute__((ext_vector_type(4)));
typedef float f32x4 __attribute__((ext_vector_type(4)));

#define MFMA16(a, b, c) __builtin_amdgcn_mfma_f32_16x16x32_bf16(a, b, c, 0, 0, 0)

static __device__ __forceinline__ bf16 f2b(float f) { return (bf16)f; }
static __device__ __forceinline__ float b2f(bf16 v) { return (float)v; }

// async global->LDS, 16B per lane. dst is wave-uniform base; HW adds lane*16.
static __device__ __forceinline__ void gload16(const void* src, void* dst) {
    __builtin_amdgcn_global_load_lds(
        (const __attribute__((address_space(1))) uint32_t*)src,
        (__attribute__((address_space(3))) uint32_t*)dst, 16, 0, 0);
}

// ---------------- fp32 -> bf16 conversion ----------------
__global__ void cvt_f32_bf16(const float* __restrict__ src, bf16* __restrict__ dst, int n4) {
    int i = blockIdx.x * blockDim.x + threadIdx.x;
    if (i >= n4) return;
    float4 v = reinterpret_cast<const float4*>(src)[i];
    bf16x4 o;
    o[0] = f2b(v.x); o[1] = f2b(v.y); o[2] = f2b(v.z); o[3] = f2b(v.w);
    reinterpret_cast<bf16x4*>(dst)[i] = o;
}

// ---------------- RoPE cos/sin table: tbl[s][i] = {cos,sin}(s * theta_i) ----------------
__global__ void rope_table(float2* __restrict__ tbl) {
    int t = blockIdx.x * blockDim.x + threadIdx.x;   // 0 .. 2048*64-1
    int i = t & 63;
    int s = t >> 6;
    float theta = expf(-9.210340371976184f * (float)(2 * i) * (1.0f / 128.0f));
    float freq = (float)s * theta;
    float sv, cv;
    sincosf(freq, &sv, &cv);
    tbl[t] = make_float2(cv, sv);
}

// ---------------- fused QKV GEMM, global_load_lds staging, fused RoPE epilogue ------------
// z=0: Q -> [bh][s][128] with rope, scale = log2(e)/sqrt(128)
// z=1: K -> [bh][s][128] with rope, scale = 1
// z=2: V -> [bh][128][s]  (transposed, no rope)
__global__ __launch_bounds__(256) void gemm_qkv(const bf16* __restrict__ X,
                                                const bf16* __restrict__ Wq,
                                                const bf16* __restrict__ Wk,
                                                const bf16* __restrict__ Wv,
                                                bf16* __restrict__ Qm,
                                                bf16* __restrict__ Km,
                                                bf16* __restrict__ Vt,
                                                const float2* __restrict__ tbl) {
    const int K = 2048;
    __shared__ bf16 As[128 * 64];   // linear [row][64], 16KB
    __shared__ bf16 Bs[128 * 64];

    const int z = blockIdx.z;
    const bf16* W = (z == 0) ? Wq : (z == 1) ? Wk : Wv;

    const int tid  = threadIdx.x;
    const int lane = tid & 63;
    const int w    = tid >> 6;
    const int wr   = (w >> 1) * 64;
    const int wc   = (w & 1) * 64;
    const int l15  = lane & 15;
    const int l4   = lane >> 4;
    const int rbase = blockIdx.x * 128;
    const int cbase = blockIdx.y * 128;

    const int srow = (lane >> 3);          // 0..7 within chunk
    const int scol = (lane & 7) * 8;       // element col within BK=64

    f32x4 acc[4][4] = {};

    for (int kt = 0; kt < K; kt += 64) {
        __syncthreads();   // prev compute done; safe to overwrite LDS
#pragma unroll
        for (int i = 0; i < 4; ++i) {
            int c   = w * 4 + i;            // chunk 0..15, 8 rows each
            int row = c * 8 + srow;
            gload16(&X[(size_t)(rbase + row) * K + kt + scol], (char*)As + c * 1024);
            gload16(&W[(size_t)(cbase + row) * K + kt + scol], (char*)Bs + c * 1024);
        }
        __syncthreads();   // vmcnt(0) drained by compiler before barrier -> tile ready

        bf16x8 af[2][4], bfr[2][4];
#pragma unroll
        for (int ks = 0; ks < 2; ++ks) {
#pragma unroll
            for (int mi = 0; mi < 4; ++mi)
                af[ks][mi] = *reinterpret_cast<const bf16x8*>(
                    (char*)As + (wr + mi * 16 + l15) * 128 + ks * 64 + l4 * 16);
#pragma unroll
            for (int ni = 0; ni < 4; ++ni)
                bfr[ks][ni] = *reinterpret_cast<const bf16x8*>(
                    (char*)Bs + (wc + ni * 16 + l15) * 128 + ks * 64 + l4 * 16);
        }
#pragma unroll
        for (int ks = 0; ks < 2; ++ks)
#pragma unroll
            for (int mi = 0; mi < 4; ++mi)
#pragma unroll
                for (int ni = 0; ni < 4; ++ni)
                    acc[mi][ni] = MFMA16(af[ks][mi], bfr[ks][ni], acc[mi][ni]);
    }

    if (z < 2) {
        // rope + scale epilogue; log2(e) folded into Q scale for exp2 softmax
        bf16* Y = (z == 0) ? Qm : Km;
        const float scale = (z == 0) ? 0.1275174396094198f : 1.0f;
        const int odd = l15 & 1;          // == d&1
#pragma unroll
        for (int mi = 0; mi < 4; ++mi) {
            int r0 = rbase + wr + mi * 16 + l4 * 4;
#pragma unroll
            for (int i = 0; i < 4; ++i) {
                int r = r0 + i;
                int b = r >> 11, s = r & 2047;
#pragma unroll
                for (int ni = 0; ni < 4; ++ni) {
                    int n = cbase + wc + ni * 16 + l15;
                    int h = n >> 7, d = n & 127;
                    float v = acc[mi][ni][i];
                    float p = __shfl_xor(v, 1);         // partner column of the rope pair
                    float2 cs = tbl[(s << 6) + (d >> 1)];
                    float res = v * cs.x + (odd ? p : -p) * cs.y;
                    Y[(((size_t)b * 16 + h) * 2048 + s) * 128 + d] = f2b(res * scale);
                }
            }
        }
    } else {
#pragma unroll
        for (int mi = 0; mi < 4; ++mi) {
            int r0 = rbase + wr + mi * 16 + l4 * 4;
            int b = r0 >> 11, s = r0 & 2047;
#pragma unroll
            for (int ni = 0; ni < 4; ++ni) {
                int n = cbase + wc + ni * 16 + l15;
                int h = n >> 7, d = n & 127;
                bf16x4 o;
#pragma unroll
                for (int i = 0; i < 4; ++i) o[i] = f2b(acc[mi][ni][i]);
                *reinterpret_cast<bf16x4*>(&Vt[(((size_t)b * 16 + h) * 128 + d) * 2048 + s]) = o;
            }
        }
    }
}

// ---------------- causal flash attention v3 ----------------
// 512 blocks, one (bh, qtile) job each; blocks b and b+256 have qt and 15-qt so
// co-resident pairs sum to a uniform 34 kv-steps. 4 waves x 32 q-rows.
// K/V double-buffered in LDS (80KB = exactly 2 blocks/CU).
__global__ __launch_bounds__(256) void flash_attn(const bf16* __restrict__ Q,
                                                  const bf16* __restrict__ Km,
                                                  const bf16* __restrict__ Vt,
                                                  float* __restrict__ out) {
    __shared__ bf16 Ksh[2][64 * 128];
    __shared__ bf16 Vsh[2][128 * 64];
    __shared__ bf16 Psh[4][32 * 64];

    const int tid  = threadIdx.x;
    const int lane = tid & 63;
    const int w    = tid >> 6;
    const int l15  = lane & 15;
    const int l4   = lane >> 4;

    const int bx = blockIdx.x;
    int bh, qt;
    if (bx < 256) { bh = bx >> 4;            qt = bx & 15; }
    else          { int u = bx - 256; bh = 16 + (u >> 4); qt = 15 - (u & 15); }
    const int b = bh >> 4, h = bh & 15;

    const bf16* Qb = Q  + (size_t)bh * 2048 * 128;
    const bf16* Kb = Km + (size_t)bh * 2048 * 128;
    const bf16* Vb = Vt + (size_t)bh * 128 * 2048;
    const int q0 = qt * 128;
    const int rw = q0 + w * 32;

    auto stage = [&](int buf, int kvb) {
        char* kd = (char*)Ksh[buf];
        char* vd = (char*)Vsh[buf];
#pragma unroll
        for (int c4 = 0; c4 < 4; ++c4) {
            int c  = w * 4 + c4;
            int kr = c * 4 + (lane >> 4);
            int ks = (lane & 15) ^ (kr & 7);
            gload16((const char*)Kb + ((size_t)(kvb + kr) * 128 + ks * 8) * 2, kd + c * 1024);
            int vr = c * 8 + (lane >> 3);
            int vs = (lane & 7) ^ (vr & 7);
            gload16((const char*)Vb + ((size_t)vr * 2048 + kvb + vs * 8) * 2, vd + c * 1024);
        }
    };

    bf16x8 qf[2][4];
#pragma unroll
    for (int qi = 0; qi < 2; ++qi)
#pragma unroll
        for (int ks = 0; ks < 4; ++ks)
            qf[qi][ks] = *reinterpret_cast<const bf16x8*>(
                &Qb[(size_t)(rw + qi * 16 + l15) * 128 + ks * 32 + l4 * 8]);

    f32x4 o[2][8] = {};
    float mrow[2][4], lrow[2][4];
#pragma unroll
    for (int qi = 0; qi < 2; ++qi)
#pragma unroll
        for (int i = 0; i < 4; ++i) { mrow[qi][i] = -1e30f; lrow[qi][i] = 0.0f; }

    const int n = 2 * qt + 2;
    stage(0, 0);
    __syncthreads();
    int cur = 0;

    for (int t = 0; t < n; ++t) {
        const int kvb = t * 64;
        if (t + 1 < n) stage(1 - cur, kvb + 64);

        const bool active = (kvb <= rw + 31);
        if (active) {
            const char* kb = (const char*)Ksh[cur];
            f32x4 sacc[2][4] = {};
#pragma unroll
            for (int ns = 0; ns < 4; ++ns) {
                int r = ns * 16 + l15;
#pragma unroll
                for (int ks = 0; ks < 4; ++ks) {
                    int phys = (ks * 4 + l4) ^ (r & 7);
                    bf16x8 kf = *reinterpret_cast<const bf16x8*>(kb + r * 256 + phys * 16);
                    sacc[0][ns] = MFMA16(qf[0][ks], kf, sacc[0][ns]);
                    sacc[1][ns] = MFMA16(qf[1][ks], kf, sacc[1][ns]);
                }
            }
            if (kvb + 63 > rw) {
#pragma unroll
                for (int qi = 0; qi < 2; ++qi)
#pragma unroll
                    for (int ns = 0; ns < 4; ++ns) {
                        int col = kvb + ns * 16 + l15;
#pragma unroll
                        for (int i = 0; i < 4; ++i) {
                            int row = rw + qi * 16 + l4 * 4 + i;
                            if (col > row) sacc[qi][ns][i] = -1e30f;
                        }
                    }
            }
            // online softmax in exp2 domain (scores pre-scaled by log2e/sqrt(d))
            char* pw = (char*)Psh[w];
#pragma unroll
            for (int qi = 0; qi < 2; ++qi)
#pragma unroll
                for (int i = 0; i < 4; ++i) {
                    float sm = fmaxf(fmaxf(sacc[qi][0][i], sacc[qi][1][i]),
                                     fmaxf(sacc[qi][2][i], sacc[qi][3][i]));
                    sm = fmaxf(sm, __shfl_xor(sm, 1));
                    sm = fmaxf(sm, __shfl_xor(sm, 2));
                    sm = fmaxf(sm, __shfl_xor(sm, 4));
                    sm = fmaxf(sm, __shfl_xor(sm, 8));
                    float nm    = fmaxf(mrow[qi][i], sm);
                    float alpha = __builtin_amdgcn_exp2f(mrow[qi][i] - nm);
                    mrow[qi][i] = nm;
                    float ps = 0.0f;
                    int r = qi * 16 + l4 * 4 + i;
                    int f = r & 7;
#pragma unroll
                    for (int ns = 0; ns < 4; ++ns) {
                        float p = __builtin_amdgcn_exp2f(sacc[qi][ns][i] - nm);
                        ps += p;
                        int col  = ns * 16 + l15;
                        int slot = (col >> 3) ^ f;
                        *(bf16*)(pw + r * 128 + slot * 16 + (col & 7) * 2) = f2b(p);
                    }
                    ps += __shfl_xor(ps, 1);
                    ps += __shfl_xor(ps, 2);
                    ps += __shfl_xor(ps, 4);
                    ps += __shfl_xor(ps, 8);
                    lrow[qi][i] = lrow[qi][i] * alpha + ps;
#pragma unroll
                    for (int ds = 0; ds < 8; ++ds) o[qi][ds][i] *= alpha;
                }
            asm volatile("s_waitcnt lgkmcnt(0)" ::: "memory");
            __builtin_amdgcn_sched_barrier(0);
            const char* vb = (const char*)Vsh[cur];
#pragma unroll
            for (int k2 = 0; k2 < 2; ++k2) {
                bf16x8 pa[2];
#pragma unroll
                for (int qi = 0; qi < 2; ++qi) {
                    int pr   = qi * 16 + l15;
                    int phys = (k2 * 4 + l4) ^ (pr & 7);
                    pa[qi] = *reinterpret_cast<const bf16x8*>(pw + pr * 128 + phys * 16);
                }
#pragma unroll
                for (int ds = 0; ds < 8; ++ds) {
                    int d    = ds * 16 + l15;
                    int phys = (k2 * 4 + l4) ^ (d & 7);
                    bf16x8 vf = *reinterpret_cast<const bf16x8*>(vb + d * 128 + phys * 16);
                    o[0][ds] = MFMA16(pa[0], vf, o[0][ds]);
                    o[1][ds] = MFMA16(pa[1], vf, o[1][ds]);
                }
            }
        }
        __syncthreads();
        cur ^= 1;
    }

#pragma unroll
    for (int qi = 0; qi < 2; ++qi)
#pragma unroll
        for (int i = 0; i < 4; ++i) {
            float inv = 1.0f / lrow[qi][i];
            int row = rw + qi * 16 + l4 * 4 + i;
#pragma unroll
            for (int ds = 0; ds < 8; ++ds)
                out[((size_t)b * 2048 + row) * 2048 + h * 128 + ds * 16 + l15] =
                    o[qi][ds][i] * inv;
        }
}

extern "C" void kernel_launch(void* const* d_in, const int* in_sizes, int n_in,
                              void* d_out, int out_size, void* d_ws, size_t ws_size,
                              hipStream_t stream) {
    const float* x  = (const float*)d_in[0];
    const float* Wq = (const float*)d_in[1];
    const float* Wk = (const float*)d_in[2];
    const float* Wv = (const float*)d_in[3];
    float* out = (float*)d_out;
    char* ws = (char*)d_ws;

    bf16* xb   = (bf16*)(ws + 0);
    bf16* wqb  = (bf16*)(ws + 16777216);
    bf16* wkb  = (bf16*)(ws + 25165824);
    bf16* wvb  = (bf16*)(ws + 33554432);
    bf16* Qm   = (bf16*)(ws + 41943040);
    bf16* Km   = (bf16*)(ws + 58720256);
    bf16* Vt   = (bf16*)(ws + 75497472);
    float2* tbl = (float2*)(ws + 92274688);

    cvt_f32_bf16<<<8192, 256, 0, stream>>>(x, xb, 2097152);
    cvt_f32_bf16<<<4096, 256, 0, stream>>>(Wq, wqb, 1048576);
    cvt_f32_bf16<<<4096, 256, 0, stream>>>(Wk, wkb, 1048576);
    cvt_f32_bf16<<<4096, 256, 0, stream>>>(Wv, wvb, 1048576);
    rope_table<<<512, 256, 0, stream>>>(tbl);

    dim3 gg(32, 16, 3);
    gemm_qkv<<<gg, 256, 0, stream>>>(xb, wqb, wkb, wvb, Qm, Km, Vt, tbl);

    flash_attn<<<512, 256, 0, stream>>>(Qm, Km, Vt, out);
}

// Round 4
// 277.138 us; speedup vs baseline: 1.2747x; 1.2747x over previous
//
#include <hip/hip_runtime.h>
#include <hip/hip_bf16.h>
#include <stdint.h>

typedef __bf16 bf16;
typedef bf16 bf16x8 __attribute__((ext_vector_type(8)));
typedef bf16 bf16x4 __attribute__((ext_vector_type(4)));
typedef float f32x4 __attribute__((ext_vector_type(4)));

#define MFMA16(a, b, c) __builtin_amdgcn_mfma_f32_16x16x32_bf16(a, b, c, 0, 0, 0)

static __device__ __forceinline__ bf16 f2b(float f) { return (bf16)f; }
static __device__ __forceinline__ float b2f(bf16 v) { return (float)v; }

// async global->LDS, 16B per lane. dst is wave-uniform base; HW adds lane*16.
static __device__ __forceinline__ void gload16(const void* src, void* dst) {
    __builtin_amdgcn_global_load_lds(
        (const __attribute__((address_space(1))) uint32_t*)src,
        (__attribute__((address_space(3))) uint32_t*)dst, 16, 0, 0);
}

// ---------------- fp32 -> bf16 conversion ----------------
__global__ void cvt_f32_bf16(const float* __restrict__ src, bf16* __restrict__ dst, int n4) {
    int i = blockIdx.x * blockDim.x + threadIdx.x;
    if (i >= n4) return;
    float4 v = reinterpret_cast<const float4*>(src)[i];
    bf16x4 o;
    o[0] = f2b(v.x); o[1] = f2b(v.y); o[2] = f2b(v.z); o[3] = f2b(v.w);
    reinterpret_cast<bf16x4*>(dst)[i] = o;
}

// ---------------- RoPE cos/sin table: tbl[s][i] = {cos,sin}(s * theta_i) ----------------
__global__ void rope_table(float2* __restrict__ tbl) {
    int t = blockIdx.x * blockDim.x + threadIdx.x;   // 0 .. 2048*64-1
    int i = t & 63;
    int s = t >> 6;
    float theta = expf(-9.210340371976184f * (float)(2 * i) * (1.0f / 128.0f));
    float freq = (float)s * theta;
    float sv, cv;
    sincosf(freq, &sv, &cv);
    tbl[t] = make_float2(cv, sv);
}

// ---------------- fused QKV GEMM, global_load_lds staging, fused RoPE epilogue ------------
// z=0: Q -> [bh][s][128] with rope, scale = log2(e)/sqrt(128)
// z=1: K -> [bh][s][128] with rope, scale = 1
// z=2: V -> [bh][128][s]  (transposed, no rope)
__global__ __launch_bounds__(256) void gemm_qkv(const bf16* __restrict__ X,
                                                const bf16* __restrict__ Wq,
                                                const bf16* __restrict__ Wk,
                                                const bf16* __restrict__ Wv,
                                                bf16* __restrict__ Qm,
                                                bf16* __restrict__ Km,
                                                bf16* __restrict__ Vt,
                                                const float2* __restrict__ tbl) {
    const int K = 2048;
    __shared__ bf16 As[128 * 64];   // linear [row][64], 16KB
    __shared__ bf16 Bs[128 * 64];

    const int z = blockIdx.z;
    const bf16* W = (z == 0) ? Wq : (z == 1) ? Wk : Wv;

    const int tid  = threadIdx.x;
    const int lane = tid & 63;
    const int w    = tid >> 6;
    const int wr   = (w >> 1) * 64;
    const int wc   = (w & 1) * 64;
    const int l15  = lane & 15;
    const int l4   = lane >> 4;
    const int rbase = blockIdx.x * 128;
    const int cbase = blockIdx.y * 128;

    const int srow = (lane >> 3);          // 0..7 within chunk
    const int scol = (lane & 7) * 8;       // element col within BK=64

    f32x4 acc[4][4] = {};

    for (int kt = 0; kt < K; kt += 64) {
        __syncthreads();
#pragma unroll
        for (int i = 0; i < 4; ++i) {
            int c   = w * 4 + i;            // chunk 0..15, 8 rows each
            int row = c * 8 + srow;
            gload16(&X[(size_t)(rbase + row) * K + kt + scol], (char*)As + c * 1024);
            gload16(&W[(size_t)(cbase + row) * K + kt + scol], (char*)Bs + c * 1024);
        }
        __syncthreads();

        bf16x8 af[2][4], bfr[2][4];
#pragma unroll
        for (int ks = 0; ks < 2; ++ks) {
#pragma unroll
            for (int mi = 0; mi < 4; ++mi)
                af[ks][mi] = *reinterpret_cast<const bf16x8*>(
                    (char*)As + (wr + mi * 16 + l15) * 128 + ks * 64 + l4 * 16);
#pragma unroll
            for (int ni = 0; ni < 4; ++ni)
                bfr[ks][ni] = *reinterpret_cast<const bf16x8*>(
                    (char*)Bs + (wc + ni * 16 + l15) * 128 + ks * 64 + l4 * 16);
        }
#pragma unroll
        for (int ks = 0; ks < 2; ++ks)
#pragma unroll
            for (int mi = 0; mi < 4; ++mi)
#pragma unroll
                for (int ni = 0; ni < 4; ++ni)
                    acc[mi][ni] = MFMA16(af[ks][mi], bfr[ks][ni], acc[mi][ni]);
    }

    if (z < 2) {
        bf16* Y = (z == 0) ? Qm : Km;
        const float scale = (z == 0) ? 0.1275174396094198f : 1.0f;  // log2e/sqrt(128) | 1
        const int odd = l15 & 1;
#pragma unroll
        for (int mi = 0; mi < 4; ++mi) {
            int r0 = rbase + wr + mi * 16 + l4 * 4;
#pragma unroll
            for (int i = 0; i < 4; ++i) {
                int r = r0 + i;
                int b = r >> 11, s = r & 2047;
#pragma unroll
                for (int ni = 0; ni < 4; ++ni) {
                    int n = cbase + wc + ni * 16 + l15;
                    int h = n >> 7, d = n & 127;
                    float v = acc[mi][ni][i];
                    float p = __shfl_xor(v, 1);
                    float2 cs = tbl[(s << 6) + (d >> 1)];
                    float res = v * cs.x + (odd ? p : -p) * cs.y;
                    Y[(((size_t)b * 16 + h) * 2048 + s) * 128 + d] = f2b(res * scale);
                }
            }
        }
    } else {
#pragma unroll
        for (int mi = 0; mi < 4; ++mi) {
            int r0 = rbase + wr + mi * 16 + l4 * 4;
            int b = r0 >> 11, s = r0 & 2047;
#pragma unroll
            for (int ni = 0; ni < 4; ++ni) {
                int n = cbase + wc + ni * 16 + l15;
                int h = n >> 7, d = n & 127;
                bf16x4 o;
#pragma unroll
                for (int i = 0; i < 4; ++i) o[i] = f2b(acc[mi][ni][i]);
                *reinterpret_cast<bf16x4*>(&Vt[(((size_t)b * 16 + h) * 128 + d) * 2048 + s]) = o;
            }
        }
    }
}

// ---------------- causal flash attention v4 ----------------
// QBLK=64 (4 waves x 16 rows), KVBLK=64 single-buffered. 40KB LDS -> 3-4 blocks/CU.
// 1024 blocks; 4-segment qt mapping makes each resident quadruple sum to 66 steps.
__global__ __launch_bounds__(256) void flash_attn(const bf16* __restrict__ Q,
                                                  const bf16* __restrict__ Km,
                                                  const bf16* __restrict__ Vt,
                                                  float* __restrict__ out) {
    __shared__ bf16 Ksh[64 * 128];    // 16KB [kv][d], swizzled 16B slots
    __shared__ bf16 Vsh[128 * 64];    // 16KB [d][kv], swizzled
    __shared__ bf16 Psh[4][16 * 64];  // 8KB per-wave P

    const int tid  = threadIdx.x;
    const int lane = tid & 63;
    const int w    = tid >> 6;
    const int l15  = lane & 15;
    const int l4   = lane >> 4;

    const int bx  = blockIdx.x;
    const int g   = (bx >> 5) & 7;
    const int seg = bx >> 8;
    const int qt  = (seg == 0) ? 31 - g : (seg == 1) ? g : (seg == 2) ? 23 - g : 8 + g;
    const int bh  = bx & 31;
    const int b   = bh >> 4, h = bh & 15;

    const bf16* Qb = Q  + (size_t)bh * 2048 * 128;
    const bf16* Kb = Km + (size_t)bh * 2048 * 128;
    const bf16* Vb = Vt + (size_t)bh * 128 * 2048;
    const int rw = qt * 64 + w * 16;

    auto stage = [&](int kvb) {
#pragma unroll
        for (int c4 = 0; c4 < 4; ++c4) {
            int c  = w * 4 + c4;
            int kr = c * 4 + (lane >> 4);
            int ks = (lane & 15) ^ (kr & 7);
            gload16((const char*)Kb + ((size_t)(kvb + kr) * 128 + ks * 8) * 2,
                    (char*)Ksh + c * 1024);
            int vr = c * 8 + (lane >> 3);
            int vs = (lane & 7) ^ (vr & 7);
            gload16((const char*)Vb + ((size_t)vr * 2048 + kvb + vs * 8) * 2,
                    (char*)Vsh + c * 1024);
        }
    };

    bf16x8 qf[4];
#pragma unroll
    for (int ks = 0; ks < 4; ++ks)
        qf[ks] = *reinterpret_cast<const bf16x8*>(
            &Qb[(size_t)(rw + l15) * 128 + ks * 32 + l4 * 8]);

    f32x4 o[8] = {};
    float mrow[4], lrow[4];
#pragma unroll
    for (int i = 0; i < 4; ++i) { mrow[i] = -1e30f; lrow[i] = 0.0f; }

    char* pw = (char*)Psh[w];

    for (int t = 0; t <= qt; ++t) {
        const int kvb = t * 64;
        __syncthreads();            // previous compute done -> safe to overwrite LDS
        stage(kvb);
        __syncthreads();            // compiler drains vmcnt before barrier -> tile ready

        const char* kb = (const char*)Ksh;
        f32x4 sacc[4] = {};
        __builtin_amdgcn_s_setprio(1);
#pragma unroll
        for (int ns = 0; ns < 4; ++ns) {
            int r = ns * 16 + l15;
#pragma unroll
            for (int ks = 0; ks < 4; ++ks) {
                int phys = (ks * 4 + l4) ^ (r & 7);
                bf16x8 kf = *reinterpret_cast<const bf16x8*>(kb + r * 256 + phys * 16);
                sacc[ns] = MFMA16(qf[ks], kf, sacc[ns]);
            }
        }
        __builtin_amdgcn_s_setprio(0);

        if (t == qt) {   // diagonal tile: causal mask
#pragma unroll
            for (int ns = 0; ns < 4; ++ns) {
                int col = kvb + ns * 16 + l15;
#pragma unroll
                for (int i = 0; i < 4; ++i) {
                    int row = rw + l4 * 4 + i;
                    if (col > row) sacc[ns][i] = -1e30f;
                }
            }
        }
        // online softmax in exp2 domain (scores pre-scaled by log2e/sqrt(d))
#pragma unroll
        for (int i = 0; i < 4; ++i) {
            float sm = fmaxf(fmaxf(sacc[0][i], sacc[1][i]), fmaxf(sacc[2][i], sacc[3][i]));
            sm = fmaxf(sm, __shfl_xor(sm, 1));
            sm = fmaxf(sm, __shfl_xor(sm, 2));
            sm = fmaxf(sm, __shfl_xor(sm, 4));
            sm = fmaxf(sm, __shfl_xor(sm, 8));
            float nm    = fmaxf(mrow[i], sm);
            float alpha = __builtin_amdgcn_exp2f(mrow[i] - nm);
            mrow[i] = nm;
            float ps = 0.0f;
            int r = l4 * 4 + i;
            int f = r & 7;
#pragma unroll
            for (int ns = 0; ns < 4; ++ns) {
                float p = __builtin_amdgcn_exp2f(sacc[ns][i] - nm);
                ps += p;
                int col  = ns * 16 + l15;
                int slot = (col >> 3) ^ f;
                *(bf16*)(pw + r * 128 + slot * 16 + (col & 7) * 2) = f2b(p);
            }
            ps += __shfl_xor(ps, 1);
            ps += __shfl_xor(ps, 2);
            ps += __shfl_xor(ps, 4);
            ps += __shfl_xor(ps, 8);
            lrow[i] = lrow[i] * alpha + ps;
#pragma unroll
            for (int ds = 0; ds < 8; ++ds) o[ds][i] *= alpha;
        }
        asm volatile("s_waitcnt lgkmcnt(0)" ::: "memory");
        __builtin_amdgcn_sched_barrier(0);
        // PV
        const char* vb = (const char*)Vsh;
        __builtin_amdgcn_s_setprio(1);
#pragma unroll
        for (int k2 = 0; k2 < 2; ++k2) {
            int pr   = l15;
            int phys = (k2 * 4 + l4) ^ (pr & 7);
            bf16x8 pa = *reinterpret_cast<const bf16x8*>(pw + pr * 128 + phys * 16);
#pragma unroll
            for (int ds = 0; ds < 8; ++ds) {
                int d     = ds * 16 + l15;
                int physv = (k2 * 4 + l4) ^ (d & 7);
                bf16x8 vf = *reinterpret_cast<const bf16x8*>(vb + d * 128 + physv * 16);
                o[ds] = MFMA16(pa, vf, o[ds]);
            }
        }
        __builtin_amdgcn_s_setprio(0);
    }

    // epilogue: normalize + store fp32
#pragma unroll
    for (int i = 0; i < 4; ++i) {
        float inv = 1.0f / lrow[i];
        int row = rw + l4 * 4 + i;
#pragma unroll
        for (int ds = 0; ds < 8; ++ds)
            out[((size_t)b * 2048 + row) * 2048 + h * 128 + ds * 16 + l15] = o[ds][i] * inv;
    }
}

extern "C" void kernel_launch(void* const* d_in, const int* in_sizes, int n_in,
                              void* d_out, int out_size, void* d_ws, size_t ws_size,
                              hipStream_t stream) {
    const float* x  = (const float*)d_in[0];
    const float* Wq = (const float*)d_in[1];
    const float* Wk = (const float*)d_in[2];
    const float* Wv = (const float*)d_in[3];
    float* out = (float*)d_out;
    char* ws = (char*)d_ws;

    bf16* xb   = (bf16*)(ws + 0);
    bf16* wqb  = (bf16*)(ws + 16777216);
    bf16* wkb  = (bf16*)(ws + 25165824);
    bf16* wvb  = (bf16*)(ws + 33554432);
    bf16* Qm   = (bf16*)(ws + 41943040);
    bf16* Km   = (bf16*)(ws + 58720256);
    bf16* Vt   = (bf16*)(ws + 75497472);
    float2* tbl = (float2*)(ws + 92274688);

    cvt_f32_bf16<<<8192, 256, 0, stream>>>(x, xb, 2097152);
    cvt_f32_bf16<<<4096, 256, 0, stream>>>(Wq, wqb, 1048576);
    cvt_f32_bf16<<<4096, 256, 0, stream>>>(Wk, wkb, 1048576);
    cvt_f32_bf16<<<4096, 256, 0, stream>>>(Wv, wvb, 1048576);
    rope_table<<<512, 256, 0, stream>>>(tbl);

    dim3 gg(32, 16, 3);
    gemm_qkv<<<gg, 256, 0, stream>>>(xb, wqb, wkb, wvb, Qm, Km, Vt, tbl);

    flash_attn<<<1024, 256, 0, stream>>>(Qm, Km, Vt, out);
}

// Round 5
// 255.226 us; speedup vs baseline: 1.3842x; 1.0859x over previous
//
#include <hip/hip_runtime.h>
#include <hip/hip_bf16.h>
#include <stdint.h>

typedef __bf16 bf16;
typedef bf16 bf16x8 __attribute__((ext_vector_type(8)));
typedef bf16 bf16x4 __attribute__((ext_vector_type(4)));
typedef float f32x4 __attribute__((ext_vector_type(4)));

#define MFMA16(a, b, c) __builtin_amdgcn_mfma_f32_16x16x32_bf16(a, b, c, 0, 0, 0)

static __device__ __forceinline__ bf16 f2b(float f) { return (bf16)f; }
static __device__ __forceinline__ float b2f(bf16 v) { return (float)v; }

// async global->LDS, 16B per lane. dst is wave-uniform base; HW adds lane*16.
static __device__ __forceinline__ void gload16(const void* src, void* dst) {
    __builtin_amdgcn_global_load_lds(
        (const __attribute__((address_space(1))) uint32_t*)src,
        (__attribute__((address_space(3))) uint32_t*)dst, 16, 0, 0);
}

// ---------------- fused fp32 -> bf16 conversion (x, Wq, Wk, Wv in one launch) ------------
__global__ void cvt_all(const float* __restrict__ x,  const float* __restrict__ wq,
                        const float* __restrict__ wk, const float* __restrict__ wv,
                        bf16* __restrict__ xb,  bf16* __restrict__ wqb,
                        bf16* __restrict__ wkb, bf16* __restrict__ wvb) {
    int i = blockIdx.x * blockDim.x + threadIdx.x;   // float4 index, 0..5242879
    const float* src; bf16* dst; int off;
    if (i < 2097152)      { src = x;  dst = xb;  off = i; }
    else if (i < 3145728) { src = wq; dst = wqb; off = i - 2097152; }
    else if (i < 4194304) { src = wk; dst = wkb; off = i - 3145728; }
    else                  { src = wv; dst = wvb; off = i - 4194304; }
    float4 v = reinterpret_cast<const float4*>(src)[off];
    bf16x4 o;
    o[0] = f2b(v.x); o[1] = f2b(v.y); o[2] = f2b(v.z); o[3] = f2b(v.w);
    reinterpret_cast<bf16x4*>(dst)[off] = o;
}

// ---------------- RoPE cos/sin table: tbl[s][i] = {cos,sin}(s * theta_i) ----------------
__global__ void rope_table(float2* __restrict__ tbl) {
    int t = blockIdx.x * blockDim.x + threadIdx.x;   // 0 .. 2048*64-1
    int i = t & 63;
    int s = t >> 6;
    float theta = expf(-9.210340371976184f * (float)(2 * i) * (1.0f / 128.0f));
    float freq = (float)s * theta;
    float sv, cv;
    sincosf(freq, &sv, &cv);
    tbl[t] = make_float2(cv, sv);
}

// ---------------- fused QKV GEMM, global_load_lds staging, fused RoPE epilogue ------------
// LDS tiles XOR-swizzled (linear dest + inverse-swizzled global source + swizzled read).
// z=0: Q -> [bh][s][128] with rope, scale = log2(e)/sqrt(128)
// z=1: K -> [bh][s][128] with rope, scale = 1
// z=2: V -> [bh][128][s]  (transposed, no rope)
__global__ __launch_bounds__(256) void gemm_qkv(const bf16* __restrict__ X,
                                                const bf16* __restrict__ Wq,
                                                const bf16* __restrict__ Wk,
                                                const bf16* __restrict__ Wv,
                                                bf16* __restrict__ Qm,
                                                bf16* __restrict__ Km,
                                                bf16* __restrict__ Vt,
                                                const float2* __restrict__ tbl) {
    const int K = 2048;
    __shared__ bf16 As[128 * 64];   // [row][8 slots of 16B], slot ^= row&7
    __shared__ bf16 Bs[128 * 64];

    const int z = blockIdx.z;
    const bf16* W = (z == 0) ? Wq : (z == 1) ? Wk : Wv;

    const int tid  = threadIdx.x;
    const int lane = tid & 63;
    const int w    = tid >> 6;
    const int wr   = (w >> 1) * 64;
    const int wc   = (w & 1) * 64;
    const int l15  = lane & 15;
    const int l4   = lane >> 4;
    const int rbase = blockIdx.x * 128;
    const int cbase = blockIdx.y * 128;

    // staging: chunk c = 8 rows x 8 slots; lane -> row c*8+(lane>>3), phys slot lane&7.
    // source column slot = phys ^ (row&7) so that LDS[r][phys] = logical slot phys^(r&7).
    const int srow = lane >> 3;
    const int sslot = lane & 7;

    f32x4 acc[4][4] = {};

    for (int kt = 0; kt < K; kt += 64) {
        __syncthreads();
#pragma unroll
        for (int i = 0; i < 4; ++i) {
            int c   = w * 4 + i;            // chunk 0..15
            int row = c * 8 + srow;
            int gsl = sslot ^ (row & 7);
            gload16(&X[(size_t)(rbase + row) * K + kt + gsl * 8], (char*)As + c * 1024);
            gload16(&W[(size_t)(cbase + row) * K + kt + gsl * 8], (char*)Bs + c * 1024);
        }
        __syncthreads();

        bf16x8 af[2][4], bfr[2][4];
#pragma unroll
        for (int ks = 0; ks < 2; ++ks) {
#pragma unroll
            for (int mi = 0; mi < 4; ++mi) {
                int r    = wr + mi * 16 + l15;
                int phys = (ks * 4 + l4) ^ (r & 7);
                af[ks][mi] = *reinterpret_cast<const bf16x8*>((char*)As + r * 128 + phys * 16);
            }
#pragma unroll
            for (int ni = 0; ni < 4; ++ni) {
                int r    = wc + ni * 16 + l15;
                int phys = (ks * 4 + l4) ^ (r & 7);
                bfr[ks][ni] = *reinterpret_cast<const bf16x8*>((char*)Bs + r * 128 + phys * 16);
            }
        }
#pragma unroll
        for (int ks = 0; ks < 2; ++ks)
#pragma unroll
            for (int mi = 0; mi < 4; ++mi)
#pragma unroll
                for (int ni = 0; ni < 4; ++ni)
                    acc[mi][ni] = MFMA16(af[ks][mi], bfr[ks][ni], acc[mi][ni]);
    }

    if (z < 2) {
        bf16* Y = (z == 0) ? Qm : Km;
        const float scale = (z == 0) ? 0.1275174396094198f : 1.0f;  // log2e/sqrt(128) | 1
        const int odd = l15 & 1;
#pragma unroll
        for (int mi = 0; mi < 4; ++mi) {
            int r0 = rbase + wr + mi * 16 + l4 * 4;
#pragma unroll
            for (int i = 0; i < 4; ++i) {
                int r = r0 + i;
                int b = r >> 11, s = r & 2047;
#pragma unroll
                for (int ni = 0; ni < 4; ++ni) {
                    int n = cbase + wc + ni * 16 + l15;
                    int h = n >> 7, d = n & 127;
                    float v = acc[mi][ni][i];
                    float p = __shfl_xor(v, 1);
                    float2 cs = tbl[(s << 6) + (d >> 1)];
                    float res = v * cs.x + (odd ? p : -p) * cs.y;
                    Y[(((size_t)b * 16 + h) * 2048 + s) * 128 + d] = f2b(res * scale);
                }
            }
        }
    } else {
#pragma unroll
        for (int mi = 0; mi < 4; ++mi) {
            int r0 = rbase + wr + mi * 16 + l4 * 4;
            int b = r0 >> 11, s = r0 & 2047;
#pragma unroll
            for (int ni = 0; ni < 4; ++ni) {
                int n = cbase + wc + ni * 16 + l15;
                int h = n >> 7, d = n & 127;
                bf16x4 o;
#pragma unroll
                for (int i = 0; i < 4; ++i) o[i] = f2b(acc[mi][ni][i]);
                *reinterpret_cast<bf16x4*>(&Vt[(((size_t)b * 16 + h) * 128 + d) * 2048 + s]) = o;
            }
        }
    }
}

// ---------------- causal flash attention v4 (unchanged from round 4) ----------------
__global__ __launch_bounds__(256) void flash_attn(const bf16* __restrict__ Q,
                                                  const bf16* __restrict__ Km,
                                                  const bf16* __restrict__ Vt,
                                                  float* __restrict__ out) {
    __shared__ bf16 Ksh[64 * 128];
    __shared__ bf16 Vsh[128 * 64];
    __shared__ bf16 Psh[4][16 * 64];

    const int tid  = threadIdx.x;
    const int lane = tid & 63;
    const int w    = tid >> 6;
    const int l15  = lane & 15;
    const int l4   = lane >> 4;

    const int bx  = blockIdx.x;
    const int g   = (bx >> 5) & 7;
    const int seg = bx >> 8;
    const int qt  = (seg == 0) ? 31 - g : (seg == 1) ? g : (seg == 2) ? 23 - g : 8 + g;
    const int bh  = bx & 31;
    const int b   = bh >> 4, h = bh & 15;

    const bf16* Qb = Q  + (size_t)bh * 2048 * 128;
    const bf16* Kb = Km + (size_t)bh * 2048 * 128;
    const bf16* Vb = Vt + (size_t)bh * 128 * 2048;
    const int rw = qt * 64 + w * 16;

    auto stage = [&](int kvb) {
#pragma unroll
        for (int c4 = 0; c4 < 4; ++c4) {
            int c  = w * 4 + c4;
            int kr = c * 4 + (lane >> 4);
            int ks = (lane & 15) ^ (kr & 7);
            gload16((const char*)Kb + ((size_t)(kvb + kr) * 128 + ks * 8) * 2,
                    (char*)Ksh + c * 1024);
            int vr = c * 8 + (lane >> 3);
            int vs = (lane & 7) ^ (vr & 7);
            gload16((const char*)Vb + ((size_t)vr * 2048 + kvb + vs * 8) * 2,
                    (char*)Vsh + c * 1024);
        }
    };

    bf16x8 qf[4];
#pragma unroll
    for (int ks = 0; ks < 4; ++ks)
        qf[ks] = *reinterpret_cast<const bf16x8*>(
            &Qb[(size_t)(rw + l15) * 128 + ks * 32 + l4 * 8]);

    f32x4 o[8] = {};
    float mrow[4], lrow[4];
#pragma unroll
    for (int i = 0; i < 4; ++i) { mrow[i] = -1e30f; lrow[i] = 0.0f; }

    char* pw = (char*)Psh[w];

    for (int t = 0; t <= qt; ++t) {
        const int kvb = t * 64;
        __syncthreads();
        stage(kvb);
        __syncthreads();

        const char* kb = (const char*)Ksh;
        f32x4 sacc[4] = {};
        __builtin_amdgcn_s_setprio(1);
#pragma unroll
        for (int ns = 0; ns < 4; ++ns) {
            int r = ns * 16 + l15;
#pragma unroll
            for (int ks = 0; ks < 4; ++ks) {
                int phys = (ks * 4 + l4) ^ (r & 7);
                bf16x8 kf = *reinterpret_cast<const bf16x8*>(kb + r * 256 + phys * 16);
                sacc[ns] = MFMA16(qf[ks], kf, sacc[ns]);
            }
        }
        __builtin_amdgcn_s_setprio(0);

        if (t == qt) {
#pragma unroll
            for (int ns = 0; ns < 4; ++ns) {
                int col = kvb + ns * 16 + l15;
#pragma unroll
                for (int i = 0; i < 4; ++i) {
                    int row = rw + l4 * 4 + i;
                    if (col > row) sacc[ns][i] = -1e30f;
                }
            }
        }
#pragma unroll
        for (int i = 0; i < 4; ++i) {
            float sm = fmaxf(fmaxf(sacc[0][i], sacc[1][i]), fmaxf(sacc[2][i], sacc[3][i]));
            sm = fmaxf(sm, __shfl_xor(sm, 1));
            sm = fmaxf(sm, __shfl_xor(sm, 2));
            sm = fmaxf(sm, __shfl_xor(sm, 4));
            sm = fmaxf(sm, __shfl_xor(sm, 8));
            float nm    = fmaxf(mrow[i], sm);
            float alpha = __builtin_amdgcn_exp2f(mrow[i] - nm);
            mrow[i] = nm;
            float ps = 0.0f;
            int r = l4 * 4 + i;
            int f = r & 7;
#pragma unroll
            for (int ns = 0; ns < 4; ++ns) {
                float p = __builtin_amdgcn_exp2f(sacc[ns][i] - nm);
                ps += p;
                int col  = ns * 16 + l15;
                int slot = (col >> 3) ^ f;
                *(bf16*)(pw + r * 128 + slot * 16 + (col & 7) * 2) = f2b(p);
            }
            ps += __shfl_xor(ps, 1);
            ps += __shfl_xor(ps, 2);
            ps += __shfl_xor(ps, 4);
            ps += __shfl_xor(ps, 8);
            lrow[i] = lrow[i] * alpha + ps;
#pragma unroll
            for (int ds = 0; ds < 8; ++ds) o[ds][i] *= alpha;
        }
        asm volatile("s_waitcnt lgkmcnt(0)" ::: "memory");
        __builtin_amdgcn_sched_barrier(0);
        const char* vb = (const char*)Vsh;
        __builtin_amdgcn_s_setprio(1);
#pragma unroll
        for (int k2 = 0; k2 < 2; ++k2) {
            int pr   = l15;
            int phys = (k2 * 4 + l4) ^ (pr & 7);
            bf16x8 pa = *reinterpret_cast<const bf16x8*>(pw + pr * 128 + phys * 16);
#pragma unroll
            for (int ds = 0; ds < 8; ++ds) {
                int d     = ds * 16 + l15;
                int physv = (k2 * 4 + l4) ^ (d & 7);
                bf16x8 vf = *reinterpret_cast<const bf16x8*>(vb + d * 128 + physv * 16);
                o[ds] = MFMA16(pa, vf, o[ds]);
            }
        }
        __builtin_amdgcn_s_setprio(0);
    }

#pragma unroll
    for (int i = 0; i < 4; ++i) {
        float inv = 1.0f / lrow[i];
        int row = rw + l4 * 4 + i;
#pragma unroll
        for (int ds = 0; ds < 8; ++ds)
            out[((size_t)b * 2048 + row) * 2048 + h * 128 + ds * 16 + l15] = o[ds][i] * inv;
    }
}

extern "C" void kernel_launch(void* const* d_in, const int* in_sizes, int n_in,
                              void* d_out, int out_size, void* d_ws, size_t ws_size,
                              hipStream_t stream) {
    const float* x  = (const float*)d_in[0];
    const float* Wq = (const float*)d_in[1];
    const float* Wk = (const float*)d_in[2];
    const float* Wv = (const float*)d_in[3];
    float* out = (float*)d_out;
    char* ws = (char*)d_ws;

    bf16* xb   = (bf16*)(ws + 0);
    bf16* wqb  = (bf16*)(ws + 16777216);
    bf16* wkb  = (bf16*)(ws + 25165824);
    bf16* wvb  = (bf16*)(ws + 33554432);
    bf16* Qm   = (bf16*)(ws + 41943040);
    bf16* Km   = (bf16*)(ws + 58720256);
    bf16* Vt   = (bf16*)(ws + 75497472);
    float2* tbl = (float2*)(ws + 92274688);

    cvt_all<<<20480, 256, 0, stream>>>(x, Wq, Wk, Wv, xb, wqb, wkb, wvb);
    rope_table<<<512, 256, 0, stream>>>(tbl);

    dim3 gg(32, 16, 3);
    gemm_qkv<<<gg, 256, 0, stream>>>(xb, wqb, wkb, wvb, Qm, Km, Vt, tbl);

    flash_attn<<<1024, 256, 0, stream>>>(Qm, Km, Vt, out);
}

// Round 6
// 242.018 us; speedup vs baseline: 1.4597x; 1.0546x over previous
//
#include <hip/hip_runtime.h>
#include <hip/hip_bf16.h>
#include <stdint.h>

typedef __bf16 bf16;
typedef bf16 bf16x8 __attribute__((ext_vector_type(8)));
typedef bf16 bf16x4 __attribute__((ext_vector_type(4)));
typedef float f32x4 __attribute__((ext_vector_type(4)));

#define MFMA16(a, b, c) __builtin_amdgcn_mfma_f32_16x16x32_bf16(a, b, c, 0, 0, 0)

static __device__ __forceinline__ bf16 f2b(float f) { return (bf16)f; }
static __device__ __forceinline__ float b2f(bf16 v) { return (float)v; }

// async global->LDS, 16B per lane. dst is wave-uniform base; HW adds lane*16.
static __device__ __forceinline__ void gload16(const void* src, void* dst) {
    __builtin_amdgcn_global_load_lds(
        (const __attribute__((address_space(1))) uint32_t*)src,
        (__attribute__((address_space(3))) uint32_t*)dst, 16, 0, 0);
}

// ---------------- fused fp32 -> bf16 conversion (x, Wq, Wk, Wv in one launch) ------------
__global__ void cvt_all(const float* __restrict__ x,  const float* __restrict__ wq,
                        const float* __restrict__ wk, const float* __restrict__ wv,
                        bf16* __restrict__ xb,  bf16* __restrict__ wqb,
                        bf16* __restrict__ wkb, bf16* __restrict__ wvb) {
    int i = blockIdx.x * blockDim.x + threadIdx.x;   // float4 index, 0..5242879
    const float* src; bf16* dst; int off;
    if (i < 2097152)      { src = x;  dst = xb;  off = i; }
    else if (i < 3145728) { src = wq; dst = wqb; off = i - 2097152; }
    else if (i < 4194304) { src = wk; dst = wkb; off = i - 3145728; }
    else                  { src = wv; dst = wvb; off = i - 4194304; }
    float4 v = reinterpret_cast<const float4*>(src)[off];
    bf16x4 o;
    o[0] = f2b(v.x); o[1] = f2b(v.y); o[2] = f2b(v.z); o[3] = f2b(v.w);
    reinterpret_cast<bf16x4*>(dst)[off] = o;
}

// ---------------- RoPE cos/sin table: tbl[s][i] = {cos,sin}(s * theta_i) ----------------
__global__ void rope_table(float2* __restrict__ tbl) {
    int t = blockIdx.x * blockDim.x + threadIdx.x;   // 0 .. 2048*64-1
    int i = t & 63;
    int s = t >> 6;
    float theta = expf(-9.210340371976184f * (float)(2 * i) * (1.0f / 128.0f));
    float freq = (float)s * theta;
    float sv, cv;
    sincosf(freq, &sv, &cv);
    tbl[t] = make_float2(cv, sv);
}

// ---------------- fused QKV GEMM, T3-minimum 2-phase: dbuf LDS + prefetch ------------
// stage(t+1) issued BEFORE compute(t); one vmcnt(0)+barrier per K-step (the
// __syncthreads drain) so DMA loads stay in flight under the MFMAs.
// LDS tiles XOR-swizzled (linear dest + inverse-swizzled global source + swizzled read).
// z=0: Q -> [bh][s][128] with rope, scale = log2(e)/sqrt(128)
// z=1: K -> [bh][s][128] with rope, scale = 1
// z=2: V -> [bh][128][s]  (transposed, no rope)
__global__ __launch_bounds__(256) void gemm_qkv(const bf16* __restrict__ X,
                                                const bf16* __restrict__ Wq,
                                                const bf16* __restrict__ Wk,
                                                const bf16* __restrict__ Wv,
                                                bf16* __restrict__ Qm,
                                                bf16* __restrict__ Km,
                                                bf16* __restrict__ Vt,
                                                const float2* __restrict__ tbl) {
    const int K = 2048;
    __shared__ bf16 As[2][128 * 64];   // [row][8 slots of 16B], slot ^= row&7; 2x16KB
    __shared__ bf16 Bs[2][128 * 64];

    const int z = blockIdx.z;
    const bf16* W = (z == 0) ? Wq : (z == 1) ? Wk : Wv;

    const int tid  = threadIdx.x;
    const int lane = tid & 63;
    const int w    = tid >> 6;
    const int wr   = (w >> 1) * 64;
    const int wc   = (w & 1) * 64;
    const int l15  = lane & 15;
    const int l4   = lane >> 4;
    const int rbase = blockIdx.x * 128;
    const int cbase = blockIdx.y * 128;

    // staging: chunk c = 8 rows x 8 slots; lane -> row c*8+(lane>>3), phys slot lane&7.
    // source slot = phys ^ (row&7) so LDS[r][phys] holds logical slot phys^(r&7).
    const int srow  = lane >> 3;
    const int sslot = lane & 7;

    f32x4 acc[4][4] = {};

    auto stage = [&](int buf, int kt) {
#pragma unroll
        for (int i = 0; i < 4; ++i) {
            int c   = w * 4 + i;            // chunk 0..15
            int row = c * 8 + srow;
            int gsl = sslot ^ (row & 7);
            gload16(&X[(size_t)(rbase + row) * K + kt + gsl * 8], (char*)As[buf] + c * 1024);
            gload16(&W[(size_t)(cbase + row) * K + kt + gsl * 8], (char*)Bs[buf] + c * 1024);
        }
    };

    stage(0, 0);
    __syncthreads();            // vmcnt(0) drain: buf0 ready
    int cur = 0;

    for (int kt = 0; kt < K; kt += 64) {
        if (kt + 64 < K) stage(cur ^ 1, kt + 64);   // prefetch in flight under compute

        bf16x8 af[2][4], bfr[2][4];
#pragma unroll
        for (int ks = 0; ks < 2; ++ks) {
#pragma unroll
            for (int mi = 0; mi < 4; ++mi) {
                int r    = wr + mi * 16 + l15;
                int phys = (ks * 4 + l4) ^ (r & 7);
                af[ks][mi] = *reinterpret_cast<const bf16x8*>(
                    (char*)As[cur] + r * 128 + phys * 16);
            }
#pragma unroll
            for (int ni = 0; ni < 4; ++ni) {
                int r    = wc + ni * 16 + l15;
                int phys = (ks * 4 + l4) ^ (r & 7);
                bfr[ks][ni] = *reinterpret_cast<const bf16x8*>(
                    (char*)Bs[cur] + r * 128 + phys * 16);
            }
        }
#pragma unroll
        for (int ks = 0; ks < 2; ++ks)
#pragma unroll
            for (int mi = 0; mi < 4; ++mi)
#pragma unroll
                for (int ni = 0; ni < 4; ++ni)
                    acc[mi][ni] = MFMA16(af[ks][mi], bfr[ks][ni], acc[mi][ni]);

        __syncthreads();        // one vmcnt(0)+barrier per K-step: prefetch landed,
        cur ^= 1;               // all reads of cur done -> safe to overwrite next iter
    }

    if (z < 2) {
        bf16* Y = (z == 0) ? Qm : Km;
        const float scale = (z == 0) ? 0.1275174396094198f : 1.0f;  // log2e/sqrt(128) | 1
        const int odd = l15 & 1;
#pragma unroll
        for (int mi = 0; mi < 4; ++mi) {
            int r0 = rbase + wr + mi * 16 + l4 * 4;
#pragma unroll
            for (int i = 0; i < 4; ++i) {
                int r = r0 + i;
                int b = r >> 11, s = r & 2047;
#pragma unroll
                for (int ni = 0; ni < 4; ++ni) {
                    int n = cbase + wc + ni * 16 + l15;
                    int h = n >> 7, d = n & 127;
                    float v = acc[mi][ni][i];
                    float p = __shfl_xor(v, 1);
                    float2 cs = tbl[(s << 6) + (d >> 1)];
                    float res = v * cs.x + (odd ? p : -p) * cs.y;
                    Y[(((size_t)b * 16 + h) * 2048 + s) * 128 + d] = f2b(res * scale);
                }
            }
        }
    } else {
#pragma unroll
        for (int mi = 0; mi < 4; ++mi) {
            int r0 = rbase + wr + mi * 16 + l4 * 4;
            int b = r0 >> 11, s = r0 & 2047;
#pragma unroll
            for (int ni = 0; ni < 4; ++ni) {
                int n = cbase + wc + ni * 16 + l15;
                int h = n >> 7, d = n & 127;
                bf16x4 o;
#pragma unroll
                for (int i = 0; i < 4; ++i) o[i] = f2b(acc[mi][ni][i]);
                *reinterpret_cast<bf16x4*>(&Vt[(((size_t)b * 16 + h) * 128 + d) * 2048 + s]) = o;
            }
        }
    }
}

// ---------------- causal flash attention v4 (unchanged from round 5) ----------------
__global__ __launch_bounds__(256) void flash_attn(const bf16* __restrict__ Q,
                                                  const bf16* __restrict__ Km,
                                                  const bf16* __restrict__ Vt,
                                                  float* __restrict__ out) {
    __shared__ bf16 Ksh[64 * 128];
    __shared__ bf16 Vsh[128 * 64];
    __shared__ bf16 Psh[4][16 * 64];

    const int tid  = threadIdx.x;
    const int lane = tid & 63;
    const int w    = tid >> 6;
    const int l15  = lane & 15;
    const int l4   = lane >> 4;

    const int bx  = blockIdx.x;
    const int g   = (bx >> 5) & 7;
    const int seg = bx >> 8;
    const int qt  = (seg == 0) ? 31 - g : (seg == 1) ? g : (seg == 2) ? 23 - g : 8 + g;
    const int bh  = bx & 31;
    const int b   = bh >> 4, h = bh & 15;

    const bf16* Qb = Q  + (size_t)bh * 2048 * 128;
    const bf16* Kb = Km + (size_t)bh * 2048 * 128;
    const bf16* Vb = Vt + (size_t)bh * 128 * 2048;
    const int rw = qt * 64 + w * 16;

    auto stage = [&](int kvb) {
#pragma unroll
        for (int c4 = 0; c4 < 4; ++c4) {
            int c  = w * 4 + c4;
            int kr = c * 4 + (lane >> 4);
            int ks = (lane & 15) ^ (kr & 7);
            gload16((const char*)Kb + ((size_t)(kvb + kr) * 128 + ks * 8) * 2,
                    (char*)Ksh + c * 1024);
            int vr = c * 8 + (lane >> 3);
            int vs = (lane & 7) ^ (vr & 7);
            gload16((const char*)Vb + ((size_t)vr * 2048 + kvb + vs * 8) * 2,
                    (char*)Vsh + c * 1024);
        }
    };

    bf16x8 qf[4];
#pragma unroll
    for (int ks = 0; ks < 4; ++ks)
        qf[ks] = *reinterpret_cast<const bf16x8*>(
            &Qb[(size_t)(rw + l15) * 128 + ks * 32 + l4 * 8]);

    f32x4 o[8] = {};
    float mrow[4], lrow[4];
#pragma unroll
    for (int i = 0; i < 4; ++i) { mrow[i] = -1e30f; lrow[i] = 0.0f; }

    char* pw = (char*)Psh[w];

    for (int t = 0; t <= qt; ++t) {
        const int kvb = t * 64;
        __syncthreads();
        stage(kvb);
        __syncthreads();

        const char* kb = (const char*)Ksh;
        f32x4 sacc[4] = {};
        __builtin_amdgcn_s_setprio(1);
#pragma unroll
        for (int ns = 0; ns < 4; ++ns) {
            int r = ns * 16 + l15;
#pragma unroll
            for (int ks = 0; ks < 4; ++ks) {
                int phys = (ks * 4 + l4) ^ (r & 7);
                bf16x8 kf = *reinterpret_cast<const bf16x8*>(kb + r * 256 + phys * 16);
                sacc[ns] = MFMA16(qf[ks], kf, sacc[ns]);
            }
        }
        __builtin_amdgcn_s_setprio(0);

        if (t == qt) {
#pragma unroll
            for (int ns = 0; ns < 4; ++ns) {
                int col = kvb + ns * 16 + l15;
#pragma unroll
                for (int i = 0; i < 4; ++i) {
                    int row = rw + l4 * 4 + i;
                    if (col > row) sacc[ns][i] = -1e30f;
                }
            }
        }
#pragma unroll
        for (int i = 0; i < 4; ++i) {
            float sm = fmaxf(fmaxf(sacc[0][i], sacc[1][i]), fmaxf(sacc[2][i], sacc[3][i]));
            sm = fmaxf(sm, __shfl_xor(sm, 1));
            sm = fmaxf(sm, __shfl_xor(sm, 2));
            sm = fmaxf(sm, __shfl_xor(sm, 4));
            sm = fmaxf(sm, __shfl_xor(sm, 8));
            float nm    = fmaxf(mrow[i], sm);
            float alpha = __builtin_amdgcn_exp2f(mrow[i] - nm);
            mrow[i] = nm;
            float ps = 0.0f;
            int r = l4 * 4 + i;
            int f = r & 7;
#pragma unroll
            for (int ns = 0; ns < 4; ++ns) {
                float p = __builtin_amdgcn_exp2f(sacc[ns][i] - nm);
                ps += p;
                int col  = ns * 16 + l15;
                int slot = (col >> 3) ^ f;
                *(bf16*)(pw + r * 128 + slot * 16 + (col & 7) * 2) = f2b(p);
            }
            ps += __shfl_xor(ps, 1);
            ps += __shfl_xor(ps, 2);
            ps += __shfl_xor(ps, 4);
            ps += __shfl_xor(ps, 8);
            lrow[i] = lrow[i] * alpha + ps;
#pragma unroll
            for (int ds = 0; ds < 8; ++ds) o[ds][i] *= alpha;
        }
        asm volatile("s_waitcnt lgkmcnt(0)" ::: "memory");
        __builtin_amdgcn_sched_barrier(0);
        const char* vb = (const char*)Vsh;
        __builtin_amdgcn_s_setprio(1);
#pragma unroll
        for (int k2 = 0; k2 < 2; ++k2) {
            int pr   = l15;
            int phys = (k2 * 4 + l4) ^ (pr & 7);
            bf16x8 pa = *reinterpret_cast<const bf16x8*>(pw + pr * 128 + phys * 16);
#pragma unroll
            for (int ds = 0; ds < 8; ++ds) {
                int d     = ds * 16 + l15;
                int physv = (k2 * 4 + l4) ^ (d & 7);
                bf16x8 vf = *reinterpret_cast<const bf16x8*>(vb + d * 128 + physv * 16);
                o[ds] = MFMA16(pa, vf, o[ds]);
            }
        }
        __builtin_amdgcn_s_setprio(0);
    }

#pragma unroll
    for (int i = 0; i < 4; ++i) {
        float inv = 1.0f / lrow[i];
        int row = rw + l4 * 4 + i;
#pragma unroll
        for (int ds = 0; ds < 8; ++ds)
            out[((size_t)b * 2048 + row) * 2048 + h * 128 + ds * 16 + l15] = o[ds][i] * inv;
    }
}

extern "C" void kernel_launch(void* const* d_in, const int* in_sizes, int n_in,
                              void* d_out, int out_size, void* d_ws, size_t ws_size,
                              hipStream_t stream) {
    const float* x  = (const float*)d_in[0];
    const float* Wq = (const float*)d_in[1];
    const float* Wk = (const float*)d_in[2];
    const float* Wv = (const float*)d_in[3];
    float* out = (float*)d_out;
    char* ws = (char*)d_ws;

    bf16* xb   = (bf16*)(ws + 0);
    bf16* wqb  = (bf16*)(ws + 16777216);
    bf16* wkb  = (bf16*)(ws + 25165824);
    bf16* wvb  = (bf16*)(ws + 33554432);
    bf16* Qm   = (bf16*)(ws + 41943040);
    bf16* Km   = (bf16*)(ws + 58720256);
    bf16* Vt   = (bf16*)(ws + 75497472);
    float2* tbl = (float2*)(ws + 92274688);

    cvt_all<<<20480, 256, 0, stream>>>(x, Wq, Wk, Wv, xb, wqb, wkb, wvb);
    rope_table<<<512, 256, 0, stream>>>(tbl);

    dim3 gg(32, 16, 3);
    gemm_qkv<<<gg, 256, 0, stream>>>(xb, wqb, wkb, wvb, Qm, Km, Vt, tbl);

    flash_attn<<<1024, 256, 0, stream>>>(Qm, Km, Vt, out);
}